// Round 1
// baseline (163.249 us; speedup 1.0000x reference)
//
#include <hip/hip_runtime.h>

// BloomStageLoss: label-smoothed CE + transition penalty, scalar mean output.
// B = 4194304 rows, C = 5 classes, fp32 inputs, int32 targets.
// Memory-bound reduction: ~100 MB read -> ~16 us floor at 6.3 TB/s.

constexpr int C = 5;

__device__ __forceinline__ float trans_w(int d) {
    // |i-j| -> {0:0, 1:0.5, 2:1.0, >=3:2.0}
    d = d < 0 ? -d : d;
    return (d == 0) ? 0.0f : (d == 1) ? 0.5f : (d == 2) ? 1.0f : 2.0f;
}

__device__ __forceinline__ float row_loss(const float a[C], int t) {
    float m = fmaxf(fmaxf(fmaxf(a[0], a[1]), fmaxf(a[2], a[3])), a[4]);
    float e0 = __expf(a[0] - m);
    float e1 = __expf(a[1] - m);
    float e2 = __expf(a[2] - m);
    float e3 = __expf(a[3] - m);
    float e4 = __expf(a[4] - m);
    float s  = e0 + e1 + e2 + e3 + e4;
    float ls = __logf(s);
    float inv = 1.0f / s;

    float lp0 = a[0] - m - ls;
    float lp1 = a[1] - m - ls;
    float lp2 = a[2] - m - ls;
    float lp3 = a[3] - m - ls;
    float lp4 = a[4] - m - ls;
    float sumlp = lp0 + lp1 + lp2 + lp3 + lp4;

    float lpt = (t == 0) ? lp0 : (t == 1) ? lp1 : (t == 2) ? lp2 : (t == 3) ? lp3 : lp4;

    // transition penalty: sum_j p_j * T[t][j]
    float pen = e0 * trans_w(t - 0) + e1 * trans_w(t - 1) + e2 * trans_w(t - 2)
              + e3 * trans_w(t - 3) + e4 * trans_w(t - 4);
    pen *= inv;

    // CE with smoothing 0.1: coeff on target = 1 - 0.1 - 0.025 = 0.875; off = 0.025
    float ce = -(0.875f * lpt + 0.025f * sumlp);
    return ce + 0.1f * pen;
}

__global__ __launch_bounds__(256) void bloom_reduce(const float* __restrict__ x,
                                                    const int* __restrict__ tgt,
                                                    double* __restrict__ acc,
                                                    int nGroups) {
    int g = blockIdx.x * blockDim.x + threadIdx.x;
    float local = 0.0f;
    if (g < nGroups) {
        const float4* x4 = (const float4*)x;
        float4 v0 = x4[g * 5 + 0];
        float4 v1 = x4[g * 5 + 1];
        float4 v2 = x4[g * 5 + 2];
        float4 v3 = x4[g * 5 + 3];
        float4 v4 = x4[g * 5 + 4];
        int4 t4 = ((const int4*)tgt)[g];

        float r0[C] = {v0.x, v0.y, v0.z, v0.w, v1.x};
        float r1[C] = {v1.y, v1.z, v1.w, v2.x, v2.y};
        float r2[C] = {v2.z, v2.w, v3.x, v3.y, v3.z};
        float r3[C] = {v3.w, v4.x, v4.y, v4.z, v4.w};

        local  = row_loss(r0, t4.x);
        local += row_loss(r1, t4.y);
        local += row_loss(r2, t4.z);
        local += row_loss(r3, t4.w);
    }

    // wave64 reduce
    #pragma unroll
    for (int off = 32; off > 0; off >>= 1)
        local += __shfl_down(local, off, 64);

    __shared__ float wsum[4];
    int lane = threadIdx.x & 63;
    int wid  = threadIdx.x >> 6;
    if (lane == 0) wsum[wid] = local;
    __syncthreads();
    if (threadIdx.x == 0) {
        double bs = (double)wsum[0] + (double)wsum[1] + (double)wsum[2] + (double)wsum[3];
        atomicAdd(acc, bs);
    }
}

__global__ void bloom_finalize(const double* __restrict__ acc,
                               const float* __restrict__ x,
                               const int* __restrict__ tgt,
                               float* __restrict__ out,
                               int tailStart, int B) {
    double s = acc[0];
    // handle any rows not covered by the 4-row groups (B % 4 != 0)
    for (int r = tailStart; r < B; ++r) {
        float a[C];
        #pragma unroll
        for (int j = 0; j < C; ++j) a[j] = x[r * C + j];
        s += (double)row_loss(a, tgt[r]);
    }
    out[0] = (float)(s / (double)B);
}

extern "C" void kernel_launch(void* const* d_in, const int* in_sizes, int n_in,
                              void* d_out, int out_size, void* d_ws, size_t ws_size,
                              hipStream_t stream) {
    const float* x  = (const float*)d_in[0];
    const int* tgt  = (const int*)d_in[1];
    float* out      = (float*)d_out;
    double* acc     = (double*)d_ws;

    int B = in_sizes[1];          // number of rows (targets count)
    int nGroups = B / 4;          // 4 rows per thread
    int tailStart = nGroups * 4;

    hipMemsetAsync(d_ws, 0, sizeof(double), stream);

    int threads = 256;
    int blocks = (nGroups + threads - 1) / threads;
    if (blocks < 1) blocks = 1;
    bloom_reduce<<<blocks, threads, 0, stream>>>(x, tgt, acc, nGroups);
    bloom_finalize<<<1, 1, 0, stream>>>(acc, x, tgt, out, tailStart, B);
}